// Round 2
// baseline (177.803 us; speedup 1.0000x reference)
//
#include <hip/hip_runtime.h>
#include <math.h>

#define NB 32768
#define NK 10
#define ND 512
#define WPB 4               // waves per block
#define GRID (NB / WPB)

// One wave (64 lanes) per batch element. Lane l owns floats [8l, 8l+8) of
// each D=512 row. All 24 row-loads (12 rows x 2 float4) are issued
// back-to-back into registers BEFORE any consumption -> max memory-level
// parallelism per wave (~24 outstanding dwordx4 loads).
__global__ __launch_bounds__(256, 4) void sgns_main(
    const int*   __restrict__ center_ids,
    const int*   __restrict__ context_ids,
    const int*   __restrict__ neg_ids,
    const float* __restrict__ center_emb,
    const float* __restrict__ context_emb,
    float*       __restrict__ partials)
{
    const int tid  = threadIdx.x;
    const int lane = tid & 63;
    const int wave = tid >> 6;
    const int b    = blockIdx.x * WPB + wave;

    // ids are wave-uniform -> scalar loads
    const float4* cvp = (const float4*)(center_emb  + (size_t)center_ids[b]  * ND) + 2 * lane;
    const float4* cp  = (const float4*)(context_emb + (size_t)context_ids[b] * ND) + 2 * lane;

    float4 r0[2 + NK], r1[2 + NK];   // 24 float4 = 96 VGPRs

    // ---- issue phase: all loads independent, no consumption in between ----
    r0[0] = cvp[0]; r1[0] = cvp[1];
    r0[1] = cp[0];  r1[1] = cp[1];
#pragma unroll
    for (int k = 0; k < NK; ++k) {
        const float4* np = (const float4*)(context_emb + (size_t)neg_ids[b * NK + k] * ND) + 2 * lane;
        r0[2 + k] = np[0];
        r1[2 + k] = np[1];
    }

    // ---- consume phase: 11 per-lane partial dots vs center vector ----
    float part[1 + NK];
#pragma unroll
    for (int i = 0; i < 1 + NK; ++i) {
        const float4 a0 = r0[0], a1 = r1[0];
        const float4 x0 = r0[1 + i], x1 = r1[1 + i];
        part[i] = a0.x * x0.x + a0.y * x0.y + a0.z * x0.z + a0.w * x0.w
                + a1.x * x1.x + a1.y * x1.y + a1.z * x1.z + a1.w * x1.w;
    }

    // butterfly reduce each dot across the 64-lane wave
#pragma unroll
    for (int i = 0; i < 1 + NK; ++i) {
        float v = part[i];
#pragma unroll
        for (int off = 32; off > 0; off >>= 1) v += __shfl_xor(v, off, 64);
        part[i] = v;
    }

    // all lanes hold full dots; compute loss uniformly (no divergence)
    float s = fminf(fmaxf(part[0], -10.0f), 10.0f);
    float loss = log1pf(expf(-s));            // -log_sigmoid(score)
#pragma unroll
    for (int k = 1; k <= NK; ++k) {
        float t = fminf(fmaxf(part[k], -10.0f), 10.0f);
        loss += log1pf(expf(t));              // -log_sigmoid(-neg_score)
    }

    __shared__ float ls[WPB];
    if (lane == 0) ls[wave] = loss;
    __syncthreads();
    if (tid == 0)
        partials[blockIdx.x] = ls[0] + ls[1] + ls[2] + ls[3];
}

// Deterministic final reduction of the 8192 per-block partials -> mean.
__global__ __launch_bounds__(1024) void sgns_finish(
    const float* __restrict__ partials, float* __restrict__ out, int n)
{
    __shared__ float ls[1024];
    float s = 0.0f;
    for (int i = threadIdx.x; i < n; i += 1024) s += partials[i];
    ls[threadIdx.x] = s;
    __syncthreads();
    for (int w = 512; w > 0; w >>= 1) {
        if (threadIdx.x < w) ls[threadIdx.x] += ls[threadIdx.x + w];
        __syncthreads();
    }
    if (threadIdx.x == 0) out[0] = ls[0] * (1.0f / (float)NB);
}

extern "C" void kernel_launch(void* const* d_in, const int* in_sizes, int n_in,
                              void* d_out, int out_size, void* d_ws, size_t ws_size,
                              hipStream_t stream) {
    const int*   center_ids  = (const int*)d_in[0];
    const int*   context_ids = (const int*)d_in[1];
    const int*   neg_ids     = (const int*)d_in[2];
    const float* center_emb  = (const float*)d_in[3];
    const float* context_emb = (const float*)d_in[4];
    float* out      = (float*)d_out;
    float* partials = (float*)d_ws;   // GRID floats = 32 KB << ws_size

    sgns_main<<<GRID, 256, 0, stream>>>(center_ids, context_ids, neg_ids,
                                        center_emb, context_emb, partials);
    sgns_finish<<<1, 1024, 0, stream>>>(partials, out, GRID);
}

// Round 3
// 125.674 us; speedup vs baseline: 1.4148x; 1.4148x over previous
//
#include <hip/hip_runtime.h>
#include <math.h>

#define NB 32768
#define NK 10
#define ND 512
#define WPB 4               // waves per block
#define GRID (NB / WPB)
#define NROW (2 + NK)       // center + context + 10 neg rows

// One wave (64 lanes) per batch element. Lane l owns floats [8l, 8l+8) of
// each D=512 row. All 24 row-loads (12 rows x 2 float4) are pinned BEFORE
// any consumption with sched_barrier(0) so the scheduler cannot sink them:
// ~24 outstanding dwordx4 loads per wave (~96 result VGPRs).
__global__ __launch_bounds__(256, 4) void sgns_main(
    const int*   __restrict__ center_ids,
    const int*   __restrict__ context_ids,
    const int*   __restrict__ neg_ids,
    const float* __restrict__ center_emb,
    const float* __restrict__ context_emb,
    float*       __restrict__ partials)
{
    const int tid  = threadIdx.x;
    const int lane = tid & 63;
    const int wave = tid >> 6;
    const int b    = blockIdx.x * WPB + wave;

    // hoist all ids (wave-uniform scalar loads) and row base pointers
    const float4* base[NROW];
    base[0] = (const float4*)(center_emb  + (size_t)center_ids[b]  * ND) + 2 * lane;
    base[1] = (const float4*)(context_emb + (size_t)context_ids[b] * ND) + 2 * lane;
#pragma unroll
    for (int k = 0; k < NK; ++k)
        base[2 + k] = (const float4*)(context_emb + (size_t)neg_ids[b * NK + k] * ND) + 2 * lane;

    __builtin_amdgcn_sched_barrier(0);

    // ---- issue phase: 24 independent dwordx4 loads, nothing may sink past ----
    float4 r0[NROW], r1[NROW];
#pragma unroll
    for (int i = 0; i < NROW; ++i) {
        r0[i] = base[i][0];
        r1[i] = base[i][1];
    }

    __builtin_amdgcn_sched_barrier(0);

    // ---- consume phase: 11 per-lane partial dots vs center vector ----
    float part[1 + NK];
#pragma unroll
    for (int i = 0; i < 1 + NK; ++i) {
        const float4 a0 = r0[0], a1 = r1[0];
        const float4 x0 = r0[1 + i], x1 = r1[1 + i];
        part[i] = a0.x * x0.x + a0.y * x0.y + a0.z * x0.z + a0.w * x0.w
                + a1.x * x1.x + a1.y * x1.y + a1.z * x1.z + a1.w * x1.w;
    }

    // butterfly reduce each dot across the 64-lane wave
#pragma unroll
    for (int i = 0; i < 1 + NK; ++i) {
        float v = part[i];
#pragma unroll
        for (int off = 32; off > 0; off >>= 1) v += __shfl_xor(v, off, 64);
        part[i] = v;
    }

    // all lanes hold full dots; compute loss uniformly (no divergence)
    float s = fminf(fmaxf(part[0], -10.0f), 10.0f);
    float loss = log1pf(expf(-s));            // -log_sigmoid(score)
#pragma unroll
    for (int k = 1; k <= NK; ++k) {
        float t = fminf(fmaxf(part[k], -10.0f), 10.0f);
        loss += log1pf(expf(t));              // -log_sigmoid(-neg_score)
    }

    __shared__ float ls[WPB];
    if (lane == 0) ls[wave] = loss;
    __syncthreads();
    if (tid == 0)
        partials[blockIdx.x] = ls[0] + ls[1] + ls[2] + ls[3];
}

// Deterministic final reduction of the 8192 per-block partials -> mean.
__global__ __launch_bounds__(1024) void sgns_finish(
    const float* __restrict__ partials, float* __restrict__ out, int n)
{
    __shared__ float ls[1024];
    float s = 0.0f;
    for (int i = threadIdx.x; i < n; i += 1024) s += partials[i];
    ls[threadIdx.x] = s;
    __syncthreads();
    for (int w = 512; w > 0; w >>= 1) {
        if (threadIdx.x < w) ls[threadIdx.x] += ls[threadIdx.x + w];
        __syncthreads();
    }
    if (threadIdx.x == 0) out[0] = ls[0] * (1.0f / (float)NB);
}

extern "C" void kernel_launch(void* const* d_in, const int* in_sizes, int n_in,
                              void* d_out, int out_size, void* d_ws, size_t ws_size,
                              hipStream_t stream) {
    const int*   center_ids  = (const int*)d_in[0];
    const int*   context_ids = (const int*)d_in[1];
    const int*   neg_ids     = (const int*)d_in[2];
    const float* center_emb  = (const float*)d_in[3];
    const float* context_emb = (const float*)d_in[4];
    float* out      = (float*)d_out;
    float* partials = (float*)d_ws;   // GRID floats = 32 KB << ws_size

    sgns_main<<<GRID, 256, 0, stream>>>(center_ids, context_ids, neg_ids,
                                        center_emb, context_emb, partials);
    sgns_finish<<<1, 1024, 0, stream>>>(partials, out, GRID);
}

// Round 4
// 119.771 us; speedup vs baseline: 1.4845x; 1.0493x over previous
//
#include <hip/hip_runtime.h>
#include <math.h>

#define NB 32768
#define NK 10
#define ND 512
#define WPB 4               // waves per block
#define GRID (NB / WPB)

// One wave per batch element; wave = 4 groups of 16 lanes.
// Each group computes one full 512-float dot per round (3 rounds cover
// ctx + 10 negs + 1 dummy). Lane li of a group owns float4s {li + 16j},
// j=0..7 -> every dwordx4 is a coalesced 256B segment per group.
__global__ __launch_bounds__(256, 3) void sgns_main(
    const int*   __restrict__ center_ids,
    const int*   __restrict__ context_ids,
    const int*   __restrict__ neg_ids,
    const float* __restrict__ center_emb,
    const float* __restrict__ context_emb,
    float*       __restrict__ partials)
{
    const int tid  = threadIdx.x;
    const int lane = tid & 63;
    const int wave = tid >> 6;
    const int grp  = lane >> 4;     // 0..3
    const int li   = lane & 15;     // lane within group
    const int b    = blockIdx.x * WPB + wave;

    const int ctx_id = context_ids[b];
    // slot s = r*4 + grp: s=0 -> positive ctx dot, s=1..10 -> neg s-1,
    // s=11 -> dummy (re-dot ctx row, loss zeroed; row is cache-hot)
    int rid[3];
#pragma unroll
    for (int r = 0; r < 3; ++r) {
        const int s = r * 4 + grp;
        rid[r] = (s == 0 || s == 11) ? ctx_id : neg_ids[b * NK + (s - 1)];
    }

    const float4* cvp = (const float4*)(center_emb  + (size_t)center_ids[b] * ND) + li;
    const float4* rpA = (const float4*)(context_emb + (size_t)rid[0] * ND) + li;
    const float4* rpB = (const float4*)(context_emb + (size_t)rid[1] * ND) + li;
    const float4* rpC = (const float4*)(context_emb + (size_t)rid[2] * ND) + li;

    __builtin_amdgcn_sched_barrier(0);

    // issue cv + round0 + round1 rows: 24 independent dwordx4 in flight
    float4 cv[8], ra[8], rb[8];
#pragma unroll
    for (int j = 0; j < 8; ++j) cv[j] = cvp[16 * j];
#pragma unroll
    for (int j = 0; j < 8; ++j) ra[j] = rpA[16 * j];
#pragma unroll
    for (int j = 0; j < 8; ++j) rb[j] = rpB[16 * j];

    __builtin_amdgcn_sched_barrier(0);

    float lacc = 0.0f;

    // ---- round 0 (consumes ra) ----
    {
        float p = 0.0f;
#pragma unroll
        for (int j = 0; j < 8; ++j)
            p += cv[j].x * ra[j].x + cv[j].y * ra[j].y
               + cv[j].z * ra[j].z + cv[j].w * ra[j].w;
#pragma unroll
        for (int off = 1; off < 16; off <<= 1) p += __shfl_xor(p, off, 64);
        float t = fminf(fmaxf(p, -10.0f), 10.0f);
        const int s = grp;                       // 0..3
        t = (s == 0) ? -t : t;
        lacc += __logf(1.0f + __expf(t));        // softplus(t)
    }

    __builtin_amdgcn_sched_barrier(0);

    // issue round-2 rows into ra's registers
#pragma unroll
    for (int j = 0; j < 8; ++j) ra[j] = rpC[16 * j];

    __builtin_amdgcn_sched_barrier(0);

    // ---- round 1 (consumes rb) ----
    {
        float p = 0.0f;
#pragma unroll
        for (int j = 0; j < 8; ++j)
            p += cv[j].x * rb[j].x + cv[j].y * rb[j].y
               + cv[j].z * rb[j].z + cv[j].w * rb[j].w;
#pragma unroll
        for (int off = 1; off < 16; off <<= 1) p += __shfl_xor(p, off, 64);
        float t = fminf(fmaxf(p, -10.0f), 10.0f);
        lacc += __logf(1.0f + __expf(t));        // slots 4..7, all negatives
    }

    // ---- round 2 (consumes ra = round-2 rows) ----
    {
        float p = 0.0f;
#pragma unroll
        for (int j = 0; j < 8; ++j)
            p += cv[j].x * ra[j].x + cv[j].y * ra[j].y
               + cv[j].z * ra[j].z + cv[j].w * ra[j].w;
#pragma unroll
        for (int off = 1; off < 16; off <<= 1) p += __shfl_xor(p, off, 64);
        float t = fminf(fmaxf(p, -10.0f), 10.0f);
        float l = __logf(1.0f + __expf(t));
        const int s = 8 + grp;                   // 8..11
        lacc += (s == 11) ? 0.0f : l;            // slot 11 is the dummy
    }

    // sum the 4 group losses across the wave
    lacc += __shfl_xor(lacc, 16, 64);
    lacc += __shfl_xor(lacc, 32, 64);

    __shared__ float ls[WPB];
    if (lane == 0) ls[wave] = lacc;
    __syncthreads();
    if (tid == 0)
        partials[blockIdx.x] = ls[0] + ls[1] + ls[2] + ls[3];
}

// Deterministic final reduction of the 8192 per-block partials -> mean.
__global__ __launch_bounds__(1024) void sgns_finish(
    const float* __restrict__ partials, float* __restrict__ out, int n)
{
    __shared__ float ls[1024];
    float s = 0.0f;
    for (int i = threadIdx.x; i < n; i += 1024) s += partials[i];
    ls[threadIdx.x] = s;
    __syncthreads();
    for (int w = 512; w > 0; w >>= 1) {
        if (threadIdx.x < w) ls[threadIdx.x] += ls[threadIdx.x + w];
        __syncthreads();
    }
    if (threadIdx.x == 0) out[0] = ls[0] * (1.0f / (float)NB);
}

extern "C" void kernel_launch(void* const* d_in, const int* in_sizes, int n_in,
                              void* d_out, int out_size, void* d_ws, size_t ws_size,
                              hipStream_t stream) {
    const int*   center_ids  = (const int*)d_in[0];
    const int*   context_ids = (const int*)d_in[1];
    const int*   neg_ids     = (const int*)d_in[2];
    const float* center_emb  = (const float*)d_in[3];
    const float* context_emb = (const float*)d_in[4];
    float* out      = (float*)d_out;
    float* partials = (float*)d_ws;   // GRID floats = 32 KB << ws_size

    sgns_main<<<GRID, 256, 0, stream>>>(center_ids, context_ids, neg_ids,
                                        center_emb, context_emb, partials);
    sgns_finish<<<1, 1024, 0, stream>>>(partials, out, GRID);
}

// Round 5
// 117.349 us; speedup vs baseline: 1.5152x; 1.0206x over previous
//
#include <hip/hip_runtime.h>
#include <math.h>

#define NB 32768
#define NK 10
#define ND 512
#define WPB 4               // waves per block
#define GRID (NB / WPB)

// One wave per batch element; wave = 4 groups of 16 lanes.
// Each group computes one full 512-float dot per round (3 rounds cover
// ctx + 10 negs + 1 dummy). Lane li of a group owns float4s {li + 16j},
// j=0..7 -> every dwordx4 is a coalesced 256B segment per group.
// NOTE: no min-waves-per-EU hint — R3/R4 showed the hint caps residency
// (Occupancy tracked the hint: 37-39% vs 67% without it).
__global__ __launch_bounds__(256) void sgns_main(
    const int*   __restrict__ center_ids,
    const int*   __restrict__ context_ids,
    const int*   __restrict__ neg_ids,
    const float* __restrict__ center_emb,
    const float* __restrict__ context_emb,
    float*       __restrict__ partials)
{
    const int tid  = threadIdx.x;
    const int lane = tid & 63;
    const int wave = tid >> 6;
    const int grp  = lane >> 4;     // 0..3
    const int li   = lane & 15;     // lane within group
    const int b    = blockIdx.x * WPB + wave;

    const int ctx_id = context_ids[b];
    // slot s = r*4 + grp: s=0 -> positive ctx dot, s=1..10 -> neg s-1,
    // s=11 -> dummy (re-dot ctx row, loss zeroed; row is cache-hot)
    int rid[3];
#pragma unroll
    for (int r = 0; r < 3; ++r) {
        const int s = r * 4 + grp;
        rid[r] = (s == 0 || s == 11) ? ctx_id : neg_ids[b * NK + (s - 1)];
    }

    const float4* cvp = (const float4*)(center_emb  + (size_t)center_ids[b] * ND) + li;
    const float4* rpA = (const float4*)(context_emb + (size_t)rid[0] * ND) + li;
    const float4* rpB = (const float4*)(context_emb + (size_t)rid[1] * ND) + li;
    const float4* rpC = (const float4*)(context_emb + (size_t)rid[2] * ND) + li;

    __builtin_amdgcn_sched_barrier(0);

    // issue cv + round0 + round1 rows: independent dwordx4 loads in flight
    float4 cv[8], ra[8], rb[8];
#pragma unroll
    for (int j = 0; j < 8; ++j) cv[j] = cvp[16 * j];
#pragma unroll
    for (int j = 0; j < 8; ++j) ra[j] = rpA[16 * j];
#pragma unroll
    for (int j = 0; j < 8; ++j) rb[j] = rpB[16 * j];

    __builtin_amdgcn_sched_barrier(0);

    float lacc = 0.0f;

    // ---- round 0 (consumes ra) ----
    {
        float p = 0.0f;
#pragma unroll
        for (int j = 0; j < 8; ++j)
            p += cv[j].x * ra[j].x + cv[j].y * ra[j].y
               + cv[j].z * ra[j].z + cv[j].w * ra[j].w;
#pragma unroll
        for (int off = 1; off < 16; off <<= 1) p += __shfl_xor(p, off, 64);
        float t = fminf(fmaxf(p, -10.0f), 10.0f);
        const int s = grp;                       // 0..3
        t = (s == 0) ? -t : t;
        lacc += __logf(1.0f + __expf(t));        // softplus(t)
    }

    __builtin_amdgcn_sched_barrier(0);

    // issue round-2 rows into ra's registers
#pragma unroll
    for (int j = 0; j < 8; ++j) ra[j] = rpC[16 * j];

    __builtin_amdgcn_sched_barrier(0);

    // ---- round 1 (consumes rb) ----
    {
        float p = 0.0f;
#pragma unroll
        for (int j = 0; j < 8; ++j)
            p += cv[j].x * rb[j].x + cv[j].y * rb[j].y
               + cv[j].z * rb[j].z + cv[j].w * rb[j].w;
#pragma unroll
        for (int off = 1; off < 16; off <<= 1) p += __shfl_xor(p, off, 64);
        float t = fminf(fmaxf(p, -10.0f), 10.0f);
        lacc += __logf(1.0f + __expf(t));        // slots 4..7, all negatives
    }

    // ---- round 2 (consumes ra = round-2 rows) ----
    {
        float p = 0.0f;
#pragma unroll
        for (int j = 0; j < 8; ++j)
            p += cv[j].x * ra[j].x + cv[j].y * ra[j].y
               + cv[j].z * ra[j].z + cv[j].w * ra[j].w;
#pragma unroll
        for (int off = 1; off < 16; off <<= 1) p += __shfl_xor(p, off, 64);
        float t = fminf(fmaxf(p, -10.0f), 10.0f);
        float l = __logf(1.0f + __expf(t));
        const int s = 8 + grp;                   // 8..11
        lacc += (s == 11) ? 0.0f : l;            // slot 11 is the dummy
    }

    // sum the 4 group losses across the wave
    lacc += __shfl_xor(lacc, 16, 64);
    lacc += __shfl_xor(lacc, 32, 64);

    __shared__ float ls[WPB];
    if (lane == 0) ls[wave] = lacc;
    __syncthreads();
    if (tid == 0)
        partials[blockIdx.x] = ls[0] + ls[1] + ls[2] + ls[3];
}

// Deterministic final reduction of the 8192 per-block partials -> mean.
__global__ __launch_bounds__(1024) void sgns_finish(
    const float* __restrict__ partials, float* __restrict__ out, int n)
{
    __shared__ float ls[1024];
    float s = 0.0f;
    for (int i = threadIdx.x; i < n; i += 1024) s += partials[i];
    ls[threadIdx.x] = s;
    __syncthreads();
    for (int w = 512; w > 0; w >>= 1) {
        if (threadIdx.x < w) ls[threadIdx.x] += ls[threadIdx.x + w];
        __syncthreads();
    }
    if (threadIdx.x == 0) out[0] = ls[0] * (1.0f / (float)NB);
}

extern "C" void kernel_launch(void* const* d_in, const int* in_sizes, int n_in,
                              void* d_out, int out_size, void* d_ws, size_t ws_size,
                              hipStream_t stream) {
    const int*   center_ids  = (const int*)d_in[0];
    const int*   context_ids = (const int*)d_in[1];
    const int*   neg_ids     = (const int*)d_in[2];
    const float* center_emb  = (const float*)d_in[3];
    const float* context_emb = (const float*)d_in[4];
    float* out      = (float*)d_out;
    float* partials = (float*)d_ws;   // GRID floats = 32 KB << ws_size

    sgns_main<<<GRID, 256, 0, stream>>>(center_ids, context_ids, neg_ids,
                                        center_emb, context_emb, partials);
    sgns_finish<<<1, 1024, 0, stream>>>(partials, out, GRID);
}

// Round 6
// 116.787 us; speedup vs baseline: 1.5225x; 1.0048x over previous
//
#include <hip/hip_runtime.h>
#include <math.h>

#define NB 32768
#define NK 10
#define ND 512
#define WPB 4               // waves per block
#define GRID (NB / WPB)

// One wave per batch element; wave = 4 groups of 16 lanes.
// Each group computes one full 512-float dot per round (3 rounds cover
// ctx + 10 negs + 1 dummy). Lane li of a group owns float4s {li + 16j}.
// ALL 32 row-loads (cv + 3 rounds x 8) are issued in ONE fenced cluster:
// vmcnt drains monotonically (ra@<=16, rb@<=8, rc@0) so every compute
// phase keeps the remaining loads in flight.
__global__ __launch_bounds__(256) void sgns_main(
    const int*   __restrict__ center_ids,
    const int*   __restrict__ context_ids,
    const int*   __restrict__ neg_ids,
    const float* __restrict__ center_emb,
    const float* __restrict__ context_emb,
    float*       __restrict__ partials)
{
    const int tid  = threadIdx.x;
    const int lane = tid & 63;
    const int wave = tid >> 6;
    const int grp  = lane >> 4;     // 0..3
    const int li   = lane & 15;     // lane within group
    const int b    = blockIdx.x * WPB + wave;

    const int ctx_id = context_ids[b];
    // slot s = r*4 + grp: s=0 -> positive ctx dot, s=1..10 -> neg s-1,
    // s=11 -> dummy (re-dot ctx row, loss zeroed; row is cache-hot)
    int rid[3];
#pragma unroll
    for (int r = 0; r < 3; ++r) {
        const int s = r * 4 + grp;
        rid[r] = (s == 0 || s == 11) ? ctx_id : neg_ids[b * NK + (s - 1)];
    }

    const float4* cvp = (const float4*)(center_emb  + (size_t)center_ids[b] * ND) + li;
    const float4* rpA = (const float4*)(context_emb + (size_t)rid[0] * ND) + li;
    const float4* rpB = (const float4*)(context_emb + (size_t)rid[1] * ND) + li;
    const float4* rpC = (const float4*)(context_emb + (size_t)rid[2] * ND) + li;

    __builtin_amdgcn_sched_barrier(0);

    // ---- single issue cluster: 32 independent dwordx4 loads in flight ----
    float4 cv[8], ra[8], rb[8], rc[8];
#pragma unroll
    for (int j = 0; j < 8; ++j) cv[j] = cvp[16 * j];
#pragma unroll
    for (int j = 0; j < 8; ++j) ra[j] = rpA[16 * j];
#pragma unroll
    for (int j = 0; j < 8; ++j) rb[j] = rpB[16 * j];
#pragma unroll
    for (int j = 0; j < 8; ++j) rc[j] = rpC[16 * j];

    __builtin_amdgcn_sched_barrier(0);

    float lacc = 0.0f;

    // ---- round 0 (cv,ra ready @ vmcnt<=16; rb,rc still in flight) ----
    {
        float p = 0.0f;
#pragma unroll
        for (int j = 0; j < 8; ++j)
            p += cv[j].x * ra[j].x + cv[j].y * ra[j].y
               + cv[j].z * ra[j].z + cv[j].w * ra[j].w;
#pragma unroll
        for (int off = 1; off < 16; off <<= 1) p += __shfl_xor(p, off, 64);
        float t = fminf(fmaxf(p, -10.0f), 10.0f);
        t = (grp == 0) ? -t : t;                 // slot 0 is the positive
        lacc += __logf(1.0f + __expf(t));        // softplus(t)
    }

    // ---- round 1 (rb ready @ vmcnt<=8; rc still in flight) ----
    {
        float p = 0.0f;
#pragma unroll
        for (int j = 0; j < 8; ++j)
            p += cv[j].x * rb[j].x + cv[j].y * rb[j].y
               + cv[j].z * rb[j].z + cv[j].w * rb[j].w;
#pragma unroll
        for (int off = 1; off < 16; off <<= 1) p += __shfl_xor(p, off, 64);
        float t = fminf(fmaxf(p, -10.0f), 10.0f);
        lacc += __logf(1.0f + __expf(t));        // slots 4..7, all negatives
    }

    // ---- round 2 (rc @ vmcnt 0) ----
    {
        float p = 0.0f;
#pragma unroll
        for (int j = 0; j < 8; ++j)
            p += cv[j].x * rc[j].x + cv[j].y * rc[j].y
               + cv[j].z * rc[j].z + cv[j].w * rc[j].w;
#pragma unroll
        for (int off = 1; off < 16; off <<= 1) p += __shfl_xor(p, off, 64);
        float t = fminf(fmaxf(p, -10.0f), 10.0f);
        float l = __logf(1.0f + __expf(t));
        lacc += (grp == 3) ? 0.0f : l;           // slot 11 is the dummy
    }

    // sum the 4 group losses across the wave
    lacc += __shfl_xor(lacc, 16, 64);
    lacc += __shfl_xor(lacc, 32, 64);

    __shared__ float ls[WPB];
    if (lane == 0) ls[wave] = lacc;
    __syncthreads();
    if (tid == 0)
        partials[blockIdx.x] = ls[0] + ls[1] + ls[2] + ls[3];
}

// Deterministic final reduction of the 8192 per-block partials -> mean.
__global__ __launch_bounds__(1024) void sgns_finish(
    const float* __restrict__ partials, float* __restrict__ out, int n)
{
    __shared__ float ls[1024];
    float s = 0.0f;
    for (int i = threadIdx.x; i < n; i += 1024) s += partials[i];
    ls[threadIdx.x] = s;
    __syncthreads();
    for (int w = 512; w > 0; w >>= 1) {
        if (threadIdx.x < w) ls[threadIdx.x] += ls[threadIdx.x + w];
        __syncthreads();
    }
    if (threadIdx.x == 0) out[0] = ls[0] * (1.0f / (float)NB);
}

extern "C" void kernel_launch(void* const* d_in, const int* in_sizes, int n_in,
                              void* d_out, int out_size, void* d_ws, size_t ws_size,
                              hipStream_t stream) {
    const int*   center_ids  = (const int*)d_in[0];
    const int*   context_ids = (const int*)d_in[1];
    const int*   neg_ids     = (const int*)d_in[2];
    const float* center_emb  = (const float*)d_in[3];
    const float* context_emb = (const float*)d_in[4];
    float* out      = (float*)d_out;
    float* partials = (float*)d_ws;   // GRID floats = 32 KB << ws_size

    sgns_main<<<GRID, 256, 0, stream>>>(center_ids, context_ids, neg_ids,
                                        center_emb, context_emb, partials);
    sgns_finish<<<1, 1024, 0, stream>>>(partials, out, GRID);
}